// Round 1
// 1636.025 us; speedup vs baseline: 1.0024x; 1.0024x over previous
//
#include <hip/hip_runtime.h>
#include <hip/hip_bf16.h>
#include <stdint.h>

#define Bh 64
#define Nn 4096
#define Dd 256
#define Kk 15
#define Hh 512
#define BN (Bh*Nn)
#define EPSN 1e-8f
#define LN_EPS 1e-5f

typedef __attribute__((ext_vector_type(8))) short short8;
typedef __attribute__((ext_vector_type(4))) float f32x4;

__device__ __forceinline__ float bflo(unsigned u){ return __uint_as_float(u << 16); }
__device__ __forceinline__ float bfhi(unsigned u){ return __uint_as_float(u & 0xffff0000u); }
__device__ __forceinline__ unsigned short f2bf(float f){
    unsigned b = __float_as_uint(f);
    b += 0x7fffu + ((b >> 16) & 1u);   // RNE
    return (unsigned short)(b >> 16);
}
__device__ __forceinline__ float sigm_(float x){ return 1.f/(1.f+__expf(-x)); }
__device__ __forceinline__ float tanh_(float x){ return 1.f - 2.f/(__expf(2.f*x)+1.f); }

__device__ __forceinline__ void async16(const void* g, void* l){
    __builtin_amdgcn_global_load_lds((const __attribute__((address_space(1))) void*)g,
                                     (__attribute__((address_space(3))) void*)l, 16, 0, 0);
}

// ---------------- workspace layout (bytes) ----------------
// PART aliases xbf (xbf dead after k_proj)
#define OFF_X    ((size_t)0)                         // xbf 134217728 ; PART (16.7MB) aliases
#define OFF_K    (OFF_X  + (size_t)BN*256*2)         // k bf16 rows of 256
#define OFF_VT   (OFF_K  + (size_t)BN*256*2)         // vT bf16 [b][256][4096]
#define OFF_WC   (OFF_VT + (size_t)BN*256*2)         // Wc bf16 512*256
#define OFF_QBF  (OFF_WC + (size_t)512*256*2)        // q bf16 [b][16][256]
#define OFF_S    (OFF_QBF+ (size_t)64*16*256*2)
#define OFF_G    (OFF_S  + (size_t)983040)
#define OFF_SN   (OFF_G  + (size_t)983040)
#define OFF_UPD  (OFF_SN + (size_t)983040)
#define OFF_ASUM (OFF_UPD+ (size_t)983040)           // 4096
#define OFF_GT   (OFF_ASUM+(size_t)4096)
#define OFF_H1   (OFF_GT + (size_t)960*1536*4)

// ---------------- prep ----------------
__global__ __launch_bounds__(256) void k_prep_wc(const float* __restrict__ Wk, const float* __restrict__ Wv,
                                                 unsigned short* __restrict__ Wc){
    int i = blockIdx.x*256 + threadIdx.x;
    int n = i >> 8, e = i & 255;
    float w = (n < 256) ? Wk[n*256+e] : Wv[(n-256)*256+e];
    Wc[i] = f2bf(w);
}

__global__ __launch_bounds__(256) void k_slots_init(const float* __restrict__ mu, const float* __restrict__ lsig,
                                                    const float* __restrict__ noise, float* __restrict__ S){
    int i = blockIdx.x*256 + threadIdx.x;
    int j = i % (Kk*Dd);
    S[i] = mu[j] + __expf(lsig[j]) * noise[i];
}

__global__ __launch_bounds__(256) void k_ln_in(const float* __restrict__ x, const float* __restrict__ g,
                                               const float* __restrict__ b, unsigned short* __restrict__ out){
    int wave = threadIdx.x >> 6, lane = threadIdx.x & 63;
    size_t row = (size_t)blockIdx.x*4 + wave;
    const float4* xr = (const float4*)(x + row*Dd);
    float4 v = xr[lane];
    float s  = v.x+v.y+v.z+v.w;
    float ss = v.x*v.x+v.y*v.y+v.z*v.z+v.w*v.w;
    for (int m=1;m<64;m<<=1){ s += __shfl_xor(s,m); ss += __shfl_xor(ss,m); }
    float mean = s*(1.f/Dd);
    float rstd = rsqrtf(ss*(1.f/Dd) - mean*mean + LN_EPS);
    float4 gv = ((const float4*)g)[lane], bv = ((const float4*)b)[lane];
    ushort4 o;
    o.x = f2bf((v.x-mean)*rstd*gv.x + bv.x);
    o.y = f2bf((v.y-mean)*rstd*gv.y + bv.y);
    o.z = f2bf((v.z-mean)*rstd*gv.z + bv.z);
    o.w = f2bf((v.w-mean)*rstd*gv.w + bv.w);
    *(ushort4*)(out + row*Dd + lane*4) = o;
}

__global__ __launch_bounds__(256) void k_ln_rows(const float* __restrict__ x, const float* __restrict__ g,
                                                 const float* __restrict__ b, float* __restrict__ out){
    int wave = threadIdx.x >> 6, lane = threadIdx.x & 63;
    size_t row = (size_t)blockIdx.x*4 + wave;
    const float4* xr = (const float4*)(x + row*Dd);
    float4 v = xr[lane];
    float s  = v.x+v.y+v.z+v.w;
    float ss = v.x*v.x+v.y*v.y+v.z*v.z+v.w*v.w;
    for (int m=1;m<64;m<<=1){ s += __shfl_xor(s,m); ss += __shfl_xor(ss,m); }
    float mean = s*(1.f/Dd);
    float rstd = rsqrtf(ss*(1.f/Dd) - mean*mean + LN_EPS);
    float4 gv = ((const float4*)g)[lane], bv = ((const float4*)b)[lane];
    float4 o;
    o.x = (v.x-mean)*rstd*gv.x + bv.x;
    o.y = (v.y-mean)*rstd*gv.y + bv.y;
    o.z = (v.z-mean)*rstd*gv.z + bv.z;
    o.w = (v.w-mean)*rstd*gv.w + bv.w;
    *(float4*)(out + row*Dd + lane*4) = o;
}

// ---------------- MFMA projection: [k | vT] = LN(x)_bf16 @ [Wk;Wv]^T ----------------
// A-panel-resident: stage full 128x256 A panel once (XOR-swizzled), ONE barrier,
// loop the 4 N-tiles with B fragments read straight from L2-resident Wc.
__global__ __launch_bounds__(512, 4) void k_proj(const unsigned short* __restrict__ A,
                                                 const unsigned short* __restrict__ Bw,
                                                 unsigned short* __restrict__ kb,
                                                 unsigned short* __restrict__ vT){
    __shared__ short As[128*256];   // 64 KB: rows of 32 chunks(16B), chunk' = chunk ^ (row&7)
    int tid = threadIdx.x;
    int w = tid >> 6, lane = tid & 63;
    int m0 = blockIdx.x*128;
    int wr = w >> 2, wc = w & 3;           // 8 waves: 2 (rows) x 4 (cols)
    int lr = lane & 15, lg = lane >> 4;

    // stage A panel: 8 rounds x 512 threads x 16B, source pre-swizzled (both-sides rule)
#pragma unroll
    for (int j=0;j<8;j++){
        int idx = j*512 + tid;            // 0..4095
        int row = idx >> 5, chp = idx & 31;
        int ch  = chp ^ (row & 7);        // involution
        async16((const char*)A + ((size_t)(m0+row)*256 + ch*8)*2, (char*)As + (size_t)idx*16);
    }
    __syncthreads();                      // single barrier; compiler drains vmcnt here

    int bb  = m0 >> 12;                   // batch (128 | 4096 so constant per block)
    int nl0 = m0 & 4095;
    int cn = lr, cr = lg*4;
    int swz = lr & 7;

#pragma unroll
    for (int nt=0; nt<4; nt++){
        f32x4 acc[4][2];
#pragma unroll
        for (int mi=0;mi<4;mi++)
#pragma unroll
            for (int ni=0;ni<2;ni++) acc[mi][ni] = (f32x4){0.f,0.f,0.f,0.f};
        const unsigned short* bw = Bw + ((size_t)(nt*128 + wc*32))*256;
#pragma unroll
        for (int ks=0;ks<8;ks++){
            short8 bf[2];
#pragma unroll
            for (int ni=0;ni<2;ni++)
                bf[ni] = *(const short8*)(bw + (size_t)(ni*16+lr)*256 + ks*32 + lg*8);
            short8 af[4];
#pragma unroll
            for (int mi=0;mi<4;mi++){
                int row = wr*64 + mi*16 + lr;
                int chp = (ks*4 + lg) ^ swz;
                af[mi] = *(const short8*)((const char*)As + row*512 + chp*16);
            }
#pragma unroll
            for (int mi=0;mi<4;mi++)
#pragma unroll
                for (int ni=0;ni<2;ni++)
                    acc[mi][ni] = __builtin_amdgcn_mfma_f32_16x16x32_bf16(af[mi], bf[ni], acc[mi][ni], 0,0,0);
        }
        if (nt < 2){
            // kbuf: rows = tokens, cols = features
#pragma unroll
            for (int mi=0;mi<4;mi++)
#pragma unroll
                for (int ni=0;ni<2;ni++)
#pragma unroll
                    for (int r=0;r<4;r++){
                        size_t gm = (size_t)m0 + wr*64 + mi*16 + cr + r;
                        int    gn = nt*128 + wc*32 + ni*16 + cn;
                        kb[gm*256 + gn] = f2bf(acc[mi][ni][r]);
                    }
        } else {
            // vT: [b][256 feat][4096 tok], ushort4 along token dim
#pragma unroll
            for (int mi=0;mi<4;mi++){
                int nl = nl0 + wr*64 + mi*16 + cr;
#pragma unroll
                for (int ni=0;ni<2;ni++){
                    int d = (nt-2)*128 + wc*32 + ni*16 + cn;
                    ushort4 o;
                    o.x = f2bf(acc[mi][ni][0]); o.y = f2bf(acc[mi][ni][1]);
                    o.z = f2bf(acc[mi][ni][2]); o.w = f2bf(acc[mi][ni][3]);
                    *(ushort4*)(vT + ((size_t)bb*256 + d)*4096 + nl) = o;
                }
            }
        }
    }
}

// ---------------- q = LN(slots) @ Wq^T -> bf16 [b][16][256] ----------------
__global__ __launch_bounds__(256) void k_q(const float* __restrict__ sn, const float* __restrict__ Wq,
                                           unsigned short* __restrict__ qbf){
    int b = blockIdx.x, c = threadIdx.x;
    const float4* wr = (const float4*)(Wq + (size_t)c*256);
    const float4* s4 = (const float4*)(sn + (size_t)b*Kk*Dd);
    float acc[15];
#pragma unroll
    for (int r=0;r<15;r++) acc[r] = 0.f;
    for (int e=0;e<64;e++){
        float4 wv = wr[e];
#pragma unroll
        for (int r=0;r<15;r++){
            float4 sv = s4[r*64+e];
            acc[r] += sv.x*wv.x + sv.y*wv.y + sv.z*wv.z + sv.w*wv.w;
        }
    }
#pragma unroll
    for (int r=0;r<15;r++) qbf[(size_t)b*4096 + r*256 + c] = f2bf(acc[r]);
    qbf[(size_t)b*4096 + 15*256 + c] = 0;
}

// ---------------- fused attention pass (MFMA) ----------------
__global__ __launch_bounds__(256) void k_attn(const unsigned short* __restrict__ kbuf,
                                              const unsigned short* __restrict__ vT,
                                              const unsigned short* __restrict__ qbf,
                                              float* __restrict__ part, float* __restrict__ asum){
    __shared__ unsigned short qls[16*264];
    __shared__ unsigned short atn[4][16*72];
    __shared__ float updR[16*260];
    __shared__ float asl[16];
    int tid = threadIdx.x;
    int w = tid >> 6, l = tid & 63;
    int b = blockIdx.y, n0 = blockIdx.x*256;
    for (int i = tid; i < 16*260; i += 256) updR[i] = 0.f;
    if (tid < 16) asl[tid] = 0.f;
    {
        const short8* qg = (const short8*)(qbf + (size_t)b*4096);
        for (int i = tid; i < 512; i += 256){
            int row = i >> 5, cc = i & 31;
            *(short8*)&qls[row*264 + cc*8] = qg[i];
        }
    }
    __syncthreads();
    int lr = l & 15, lg = l >> 4;
    // phase 1: logits 16s x 64n per wave
    f32x4 acc[4];
#pragma unroll
    for (int t=0;t<4;t++) acc[t] = (f32x4){0.f,0.f,0.f,0.f};
    const unsigned short* kb = kbuf + ((size_t)(b*Nn) + n0 + w*64)*256;
#pragma unroll
    for (int ks=0; ks<8; ks++){
        short8 af = *(const short8*)&qls[lr*264 + ks*32 + lg*8];
#pragma unroll
        for (int t=0;t<4;t++){
            short8 bf = *(const short8*)(kb + ((size_t)(t*16+lr))*256 + ks*32 + lg*8);
            acc[t] = __builtin_amdgcn_mfma_f32_16x16x32_bf16(af, bf, acc[t], 0,0,0);
        }
    }
    // softmax over slots (per column n), write attn to LDS (bf16, A-layout ready)
    float asr[4] = {0.f,0.f,0.f,0.f};
#pragma unroll
    for (int t=0;t<4;t++){
        float v0=acc[t][0], v1=acc[t][1], v2=acc[t][2], v3=acc[t][3];
        if (lg==3) v3 = -1e30f;
        float m = fmaxf(fmaxf(v0,v1), fmaxf(v2,v3));
        m = fmaxf(m, __shfl_xor(m,16));
        m = fmaxf(m, __shfl_xor(m,32));
        float e0=__expf((v0-m)*0.0625f), e1=__expf((v1-m)*0.0625f),
              e2=__expf((v2-m)*0.0625f), e3=(lg==3)?0.f:__expf((v3-m)*0.0625f);
        float s = e0+e1+e2+e3;
        s += __shfl_xor(s,16); s += __shfl_xor(s,32);
        float inv = 1.f/s;
        e0*=inv; e1*=inv; e2*=inv; e3*=inv;
        unsigned short* a_ = &atn[w][0];
        int col = t*16 + lr;
        a_[(lg*4+0)*72+col] = f2bf(e0);
        a_[(lg*4+1)*72+col] = f2bf(e1);
        a_[(lg*4+2)*72+col] = f2bf(e2);
        a_[(lg*4+3)*72+col] = f2bf(e3);
        float p0=e0,p1=e1,p2=e2,p3=e3;
        for (int mk=1;mk<16;mk<<=1){
            p0+=__shfl_xor(p0,mk); p1+=__shfl_xor(p1,mk);
            p2+=__shfl_xor(p2,mk); p3+=__shfl_xor(p3,mk);
        }
        asr[0]+=p0; asr[1]+=p1; asr[2]+=p2; asr[3]+=p3;
    }
    if (lr == 0){
        atomicAdd(&asl[lg*4+0], asr[0]);
        atomicAdd(&asl[lg*4+1], asr[1]);
        atomicAdd(&asl[lg*4+2], asr[2]);
        atomicAdd(&asl[lg*4+3], asr[3]);
    }
    // phase 2: updates 16s x 256d per wave via MFMA over its 64-n window
    f32x4 ua[16];
#pragma unroll
    for (int dt=0;dt<16;dt++) ua[dt] = (f32x4){0.f,0.f,0.f,0.f};
    const unsigned short* vb = vT + (size_t)b*256*4096 + n0 + w*64;
#pragma unroll
    for (int kc=0;kc<2;kc++){
        short8 af = *(const short8*)&atn[w][lr*72 + kc*32 + lg*8];
#pragma unroll
        for (int dt=0;dt<16;dt++){
            short8 bf = *(const short8*)(vb + ((size_t)(dt*16+lr))*4096 + kc*32 + lg*8);
            ua[dt] = __builtin_amdgcn_mfma_f32_16x16x32_bf16(af, bf, ua[dt], 0,0,0);
        }
    }
#pragma unroll
    for (int dt=0;dt<16;dt++)
#pragma unroll
        for (int r=0;r<4;r++)
            atomicAdd(&updR[(lg*4+r)*260 + dt*16 + lr], ua[dt][r]);
    __syncthreads();
    float* pb = part + ((size_t)(b*16 + blockIdx.x))*4096;
    for (int s=0;s<16;s++) pb[s*256 + tid] = updR[s*260 + tid];
    if (tid < 15) atomicAdd(&asum[b*15+tid], asl[tid]);
}

__global__ __launch_bounds__(256) void k_upd_reduce(const float* __restrict__ part, float* __restrict__ upd){
    int i = blockIdx.x*256 + threadIdx.x;   // < 245760
    int b = i / 3840, rem = i - b*3840;
    const float* p = part + (size_t)b*16*4096 + rem;
    float s = 0.f;
#pragma unroll
    for (int j=0;j<16;j++) s += p[j*4096];
    upd[i] = s;
}

// ---------------- GRU gates ----------------
__global__ __launch_bounds__(256) void k_gates(const float* __restrict__ upd, const float* __restrict__ asum,
                                               const float* __restrict__ S,
                                               const float* __restrict__ wih, const float* __restrict__ whh,
                                               const float* __restrict__ bih, const float* __restrict__ bhh,
                                               float* __restrict__ gates){
    int b = blockIdx.y;
    int c = blockIdx.x*256 + threadIdx.x;
    bool isGI = (c < 768);
    const float* wrow = isGI ? (wih + (size_t)c*256) : (whh + (size_t)(c-768)*256);
    const float* src  = isGI ? (upd + (size_t)b*Kk*Dd) : (S + (size_t)b*Kk*Dd);
    float bias = isGI ? bih[c] : bhh[c-768];
    const float4* w4 = (const float4*)wrow;
    const float4* s4 = (const float4*)src;
    float acc[15];
#pragma unroll
    for (int r=0;r<15;r++) acc[r] = 0.f;
    for (int e=0;e<64;e++){
        float4 wv = w4[e];
#pragma unroll
        for (int r=0;r<15;r++){
            float4 sv = s4[r*64+e];
            acc[r] += sv.x*wv.x + sv.y*wv.y + sv.z*wv.z + sv.w*wv.w;
        }
    }
#pragma unroll
    for (int r=0;r<15;r++){
        float v = acc[r];
        if (isGI) v *= 1.f/(asum[b*Kk+r] + EPSN);
        gates[((size_t)(b*Kk+r))*1536 + c] = v + bias;
    }
}

__global__ __launch_bounds__(256) void k_gru(const float* __restrict__ gates, const float* __restrict__ S,
                                             float* __restrict__ G){
    int row = blockIdx.x, d = threadIdx.x;
    const float* gr = gates + (size_t)row*1536;
    float ir=gr[d], iz=gr[256+d], inn=gr[512+d];
    float hr=gr[768+d], hz=gr[1024+d], hn=gr[1280+d];
    float r = sigm_(ir+hr), z = sigm_(iz+hz);
    float n = tanh_(inn + r*hn);
    float h = S[(size_t)row*Dd + d];
    G[(size_t)row*Dd + d] = (1.f-z)*n + z*h;
}

__global__ __launch_bounds__(256) void k_mlp1(const float* __restrict__ sn, const float* __restrict__ w1,
                                              const float* __restrict__ b1, float* __restrict__ h1){
    int b = blockIdx.y;
    int c = blockIdx.x*256 + threadIdx.x;
    const float4* w4 = (const float4*)(w1 + (size_t)c*256);
    const float4* s4 = (const float4*)(sn + (size_t)b*Kk*Dd);
    float acc[15];
#pragma unroll
    for (int r=0;r<15;r++) acc[r] = 0.f;
    for (int e=0;e<64;e++){
        float4 wv = w4[e];
#pragma unroll
        for (int r=0;r<15;r++){
            float4 sv = s4[r*64+e];
            acc[r] += sv.x*wv.x + sv.y*wv.y + sv.z*wv.z + sv.w*wv.w;
        }
    }
    float bias = b1[c];
#pragma unroll
    for (int r=0;r<15;r++)
        h1[((size_t)(b*Kk+r))*Hh + c] = fmaxf(acc[r] + bias, 0.f);
}

__global__ __launch_bounds__(256) void k_mlp2(const float* __restrict__ G, const float* __restrict__ h1,
                                              const float* __restrict__ w2, const float* __restrict__ b2,
                                              float* __restrict__ S){
    int b = blockIdx.x, c = threadIdx.x;
    const float4* w4 = (const float4*)(w2 + (size_t)c*512);
    const float4* h4 = (const float4*)(h1 + (size_t)b*Kk*Hh);
    float acc[15];
#pragma unroll
    for (int r=0;r<15;r++) acc[r] = 0.f;
    for (int e=0;e<128;e++){
        float4 wv = w4[e];
#pragma unroll
        for (int r=0;r<15;r++){
            float4 hv = h4[r*128+e];
            acc[r] += hv.x*wv.x + hv.y*wv.y + hv.z*wv.z + hv.w*wv.w;
        }
    }
    float bias = b2[c];
#pragma unroll
    for (int r=0;r<15;r++){
        size_t i = ((size_t)(b*Kk+r))*Dd + c;
        S[i] = G[i] + acc[r] + bias;
    }
}

// ---------------- final attention output (MFMA logits + softmax) ----------------
__global__ __launch_bounds__(256) void k_attn_out(const unsigned short* __restrict__ kbuf,
                                                  const unsigned short* __restrict__ qbf,
                                                  float* __restrict__ out){
    __shared__ unsigned short qls[16*264];
    int tid = threadIdx.x;
    int w = tid >> 6, l = tid & 63;
    int b = blockIdx.y, n0 = blockIdx.x*256;
    {
        const short8* qg = (const short8*)(qbf + (size_t)b*4096);
        for (int i = tid; i < 512; i += 256){
            int row = i >> 5, cc = i & 31;
            *(short8*)&qls[row*264 + cc*8] = qg[i];
        }
    }
    __syncthreads();
    int lr = l & 15, lg = l >> 4;
    f32x4 acc[4];
#pragma unroll
    for (int t=0;t<4;t++) acc[t] = (f32x4){0.f,0.f,0.f,0.f};
    const unsigned short* kb = kbuf + ((size_t)(b*Nn) + n0 + w*64)*256;
#pragma unroll
    for (int ks=0; ks<8; ks++){
        short8 af = *(const short8*)&qls[lr*264 + ks*32 + lg*8];
#pragma unroll
        for (int t=0;t<4;t++){
            short8 bf = *(const short8*)(kb + ((size_t)(t*16+lr))*256 + ks*32 + lg*8);
            acc[t] = __builtin_amdgcn_mfma_f32_16x16x32_bf16(af, bf, acc[t], 0,0,0);
        }
    }
#pragma unroll
    for (int t=0;t<4;t++){
        float v0=acc[t][0], v1=acc[t][1], v2=acc[t][2], v3=acc[t][3];
        if (lg==3) v3 = -1e30f;
        float m = fmaxf(fmaxf(v0,v1), fmaxf(v2,v3));
        m = fmaxf(m, __shfl_xor(m,16));
        m = fmaxf(m, __shfl_xor(m,32));
        float e0=__expf((v0-m)*0.0625f), e1=__expf((v1-m)*0.0625f),
              e2=__expf((v2-m)*0.0625f), e3=(lg==3)?0.f:__expf((v3-m)*0.0625f);
        float s = e0+e1+e2+e3;
        s += __shfl_xor(s,16); s += __shfl_xor(s,32);
        float inv = 1.f/s;
        int n = n0 + w*64 + t*16 + lr;
        float ee0=e0*inv, ee1=e1*inv, ee2=e2*inv, ee3=e3*inv;
        out[((size_t)(b*15 + lg*4+0))*4096 + n] = ee0;
        out[((size_t)(b*15 + lg*4+1))*4096 + n] = ee1;
        out[((size_t)(b*15 + lg*4+2))*4096 + n] = ee2;
        if (lg != 3) out[((size_t)(b*15 + lg*4+3))*4096 + n] = ee3;
    }
}

__global__ __launch_bounds__(256) void k_copy(const float* __restrict__ src, float* __restrict__ dst){
    int i = blockIdx.x*256 + threadIdx.x;
    dst[i] = src[i];
}

extern "C" void kernel_launch(void* const* d_in, const int* in_sizes, int n_in,
                              void* d_out, int out_size, void* d_ws, size_t ws_size,
                              hipStream_t stream) {
    const float* inputs = (const float*)d_in[0];
    const float* noise  = (const float*)d_in[1];
    const float* mu     = (const float*)d_in[2];
    const float* lsig   = (const float*)d_in[3];
    const float* Wq     = (const float*)d_in[4];
    const float* Wk     = (const float*)d_in[5];
    const float* Wv     = (const float*)d_in[6];
    const float* wih    = (const float*)d_in[7];
    const float* whh    = (const float*)d_in[8];
    const float* bih    = (const float*)d_in[9];
    const float* bhh    = (const float*)d_in[10];
    const float* w1     = (const float*)d_in[11];
    const float* b1     = (const float*)d_in[12];
    const float* w2     = (const float*)d_in[13];
    const float* b2     = (const float*)d_in[14];
    const float* lin_w  = (const float*)d_in[15];
    const float* lin_b  = (const float*)d_in[16];
    const float* lsl_w  = (const float*)d_in[17];
    const float* lsl_b  = (const float*)d_in[18];
    const float* lml_w  = (const float*)d_in[19];
    const float* lml_b  = (const float*)d_in[20];

    char* ws = (char*)d_ws;
    unsigned short* xbf  = (unsigned short*)(ws + OFF_X);
    float*          PART = (float*)(ws + OFF_X);       // aliases xbf (dead after k_proj)
    unsigned short* kbuf = (unsigned short*)(ws + OFF_K);
    unsigned short* vT   = (unsigned short*)(ws + OFF_VT);
    unsigned short* wc   = (unsigned short*)(ws + OFF_WC);
    unsigned short* QBF  = (unsigned short*)(ws + OFF_QBF);
    float* S    = (float*)(ws + OFF_S);
    float* G    = (float*)(ws + OFF_G);
    float* SN   = (float*)(ws + OFF_SN);
    float* UPD  = (float*)(ws + OFF_UPD);
    float* ASUM = (float*)(ws + OFF_ASUM);
    float* GT   = (float*)(ws + OFF_GT);
    float* H1   = (float*)(ws + OFF_H1);
    float* out  = (float*)d_out;

    k_prep_wc<<<512, 256, 0, stream>>>(Wk, Wv, wc);
    k_slots_init<<<960, 256, 0, stream>>>(mu, lsig, noise, S);
    k_ln_in<<<BN/4, 256, 0, stream>>>(inputs, lin_w, lin_b, xbf);
    k_proj<<<BN/128, 512, 0, stream>>>(xbf, wc, kbuf, vT);

    for (int it = 0; it < 3; it++){
        k_ln_rows<<<240, 256, 0, stream>>>(S, lsl_w, lsl_b, SN);
        k_q<<<Bh, 256, 0, stream>>>(SN, Wq, QBF);
        hipMemsetAsync(ASUM, 0, 4096, stream);
        k_attn<<<dim3(16, Bh), 256, 0, stream>>>(kbuf, vT, QBF, PART, ASUM);
        k_upd_reduce<<<960, 256, 0, stream>>>(PART, UPD);
        k_gates<<<dim3(6, Bh), 256, 0, stream>>>(UPD, ASUM, S, wih, whh, bih, bhh, GT);
        k_gru<<<960, 256, 0, stream>>>(GT, S, G);
        k_ln_rows<<<240, 256, 0, stream>>>(G, lml_w, lml_b, SN);
        k_mlp1<<<dim3(2, Bh), 256, 0, stream>>>(SN, w1, b1, H1);
        k_mlp2<<<Bh, 256, 0, stream>>>(G, H1, w2, b2, S);
    }

    k_ln_rows<<<240, 256, 0, stream>>>(S, lsl_w, lsl_b, SN);
    k_q<<<Bh, 256, 0, stream>>>(SN, Wq, QBF);
    k_attn_out<<<dim3(16, Bh), 256, 0, stream>>>(kbuf, QBF, out + 245760);
    k_copy<<<960, 256, 0, stream>>>(S, out);
}

// Round 2
// 1442.291 us; speedup vs baseline: 1.1370x; 1.1343x over previous
//
#include <hip/hip_runtime.h>
#include <hip/hip_bf16.h>
#include <stdint.h>

#define Bh 64
#define Nn 4096
#define Dd 256
#define Kk 15
#define Hh 512
#define BN (Bh*Nn)
#define EPSN 1e-8f
#define LN_EPS 1e-5f

typedef __attribute__((ext_vector_type(8))) short short8;
typedef __attribute__((ext_vector_type(4))) float f32x4;

__device__ __forceinline__ float bflo(unsigned u){ return __uint_as_float(u << 16); }
__device__ __forceinline__ float bfhi(unsigned u){ return __uint_as_float(u & 0xffff0000u); }
__device__ __forceinline__ unsigned short f2bf(float f){
    unsigned b = __float_as_uint(f);
    b += 0x7fffu + ((b >> 16) & 1u);   // RNE
    return (unsigned short)(b >> 16);
}
__device__ __forceinline__ float sigm_(float x){ return 1.f/(1.f+__expf(-x)); }
__device__ __forceinline__ float tanh_(float x){ return 1.f - 2.f/(__expf(2.f*x)+1.f); }

__device__ __forceinline__ void async16(const void* g, void* l){
    __builtin_amdgcn_global_load_lds((const __attribute__((address_space(1))) void*)g,
                                     (__attribute__((address_space(3))) void*)l, 16, 0, 0);
}

// ---------------- workspace layout (bytes) ----------------
// PART aliases xbf (xbf dead after k_proj)
#define OFF_X    ((size_t)0)                         // xbf 134217728 ; PART (16.7MB) aliases
#define OFF_K    (OFF_X  + (size_t)BN*256*2)         // k bf16 rows of 256
#define OFF_VT   (OFF_K  + (size_t)BN*256*2)         // vT bf16 [b][256][4096]
#define OFF_WC   (OFF_VT + (size_t)BN*256*2)         // Wc bf16 512*256
#define OFF_QBF  (OFF_WC + (size_t)512*256*2)        // q bf16 [b][16][256]
#define OFF_S    (OFF_QBF+ (size_t)64*16*256*2)
#define OFF_G    (OFF_S  + (size_t)983040)
#define OFF_SN   (OFF_G  + (size_t)983040)
#define OFF_UPD  (OFF_SN + (size_t)983040)
#define OFF_ASUM (OFF_UPD+ (size_t)983040)           // 4096
#define OFF_GT   (OFF_ASUM+(size_t)4096)
#define OFF_H1   (OFF_GT + (size_t)960*1536*4)

// ---------------- prep ----------------
__global__ __launch_bounds__(256) void k_prep_wc(const float* __restrict__ Wk, const float* __restrict__ Wv,
                                                 unsigned short* __restrict__ Wc){
    int i = blockIdx.x*256 + threadIdx.x;
    int n = i >> 8, e = i & 255;
    float w = (n < 256) ? Wk[n*256+e] : Wv[(n-256)*256+e];
    Wc[i] = f2bf(w);
}

__global__ __launch_bounds__(256) void k_slots_init(const float* __restrict__ mu, const float* __restrict__ lsig,
                                                    const float* __restrict__ noise, float* __restrict__ S){
    int i = blockIdx.x*256 + threadIdx.x;
    int j = i % (Kk*Dd);
    S[i] = mu[j] + __expf(lsig[j]) * noise[i];
}

__global__ __launch_bounds__(256) void k_ln_in(const float* __restrict__ x, const float* __restrict__ g,
                                               const float* __restrict__ b, unsigned short* __restrict__ out){
    int wave = threadIdx.x >> 6, lane = threadIdx.x & 63;
    size_t row = (size_t)blockIdx.x*4 + wave;
    const float4* xr = (const float4*)(x + row*Dd);
    float4 v = xr[lane];
    float s  = v.x+v.y+v.z+v.w;
    float ss = v.x*v.x+v.y*v.y+v.z*v.z+v.w*v.w;
    for (int m=1;m<64;m<<=1){ s += __shfl_xor(s,m); ss += __shfl_xor(ss,m); }
    float mean = s*(1.f/Dd);
    float rstd = rsqrtf(ss*(1.f/Dd) - mean*mean + LN_EPS);
    float4 gv = ((const float4*)g)[lane], bv = ((const float4*)b)[lane];
    ushort4 o;
    o.x = f2bf((v.x-mean)*rstd*gv.x + bv.x);
    o.y = f2bf((v.y-mean)*rstd*gv.y + bv.y);
    o.z = f2bf((v.z-mean)*rstd*gv.z + bv.z);
    o.w = f2bf((v.w-mean)*rstd*gv.w + bv.w);
    *(ushort4*)(out + row*Dd + lane*4) = o;
}

__global__ __launch_bounds__(256) void k_ln_rows(const float* __restrict__ x, const float* __restrict__ g,
                                                 const float* __restrict__ b, float* __restrict__ out){
    int wave = threadIdx.x >> 6, lane = threadIdx.x & 63;
    size_t row = (size_t)blockIdx.x*4 + wave;
    const float4* xr = (const float4*)(x + row*Dd);
    float4 v = xr[lane];
    float s  = v.x+v.y+v.z+v.w;
    float ss = v.x*v.x+v.y*v.y+v.z*v.z+v.w*v.w;
    for (int m=1;m<64;m<<=1){ s += __shfl_xor(s,m); ss += __shfl_xor(ss,m); }
    float mean = s*(1.f/Dd);
    float rstd = rsqrtf(ss*(1.f/Dd) - mean*mean + LN_EPS);
    float4 gv = ((const float4*)g)[lane], bv = ((const float4*)b)[lane];
    float4 o;
    o.x = (v.x-mean)*rstd*gv.x + bv.x;
    o.y = (v.y-mean)*rstd*gv.y + bv.y;
    o.z = (v.z-mean)*rstd*gv.z + bv.z;
    o.w = (v.w-mean)*rstd*gv.w + bv.w;
    *(float4*)(out + row*Dd + lane*4) = o;
}

// ---------------- MFMA projection: [k | vT] = LN(x)_bf16 @ [Wk;Wv]^T ----------------
// A-panel-resident + explicit B-register double-buffered half-tile pipeline:
// issue next half-tile's 8 B-loads before computing current (T3/T4 counted-vmcnt pattern).
__global__ __launch_bounds__(512, 4) void k_proj(const unsigned short* __restrict__ A,
                                                 const unsigned short* __restrict__ Bw,
                                                 unsigned short* __restrict__ kb,
                                                 unsigned short* __restrict__ vT){
    __shared__ short As[128*256];   // 64 KB: rows of 32 chunks(16B), chunk' = chunk ^ (row&7)
    int tid = threadIdx.x;
    int w = tid >> 6, lane = tid & 63;
    int m0 = blockIdx.x*128;
    int wr = w >> 2, wc = w & 3;           // 8 waves: 2 (rows) x 4 (cols)
    int lr = lane & 15, lg = lane >> 4;

    // stage A panel: 8 rounds x 512 threads x 16B, source pre-swizzled (both-sides rule)
#pragma unroll
    for (int j=0;j<8;j++){
        int idx = j*512 + tid;            // 0..4095
        int row = idx >> 5, chp = idx & 31;
        int ch  = chp ^ (row & 7);        // involution
        async16((const char*)A + ((size_t)(m0+row)*256 + ch*8)*2, (char*)As + (size_t)idx*16);
    }

    // B fragment lane base: offsets (elements): nt*32768 + hf*128 + ni*4096 + kq*32
    const unsigned short* bwl = Bw + (size_t)(wc*32 + lr)*256 + lg*8;

    short8 bfb[2][4][2];                   // double buffer: 4 kq x 2 ni x 16B
#define LOADH(buf, h_) do{ int nt_=(h_)>>1, hf_=(h_)&1; \
    const unsigned short* bp_ = bwl + (size_t)nt_*32768 + hf_*128; \
    _Pragma("unroll") for (int kq_=0;kq_<4;kq_++) \
    _Pragma("unroll") for (int ni_=0;ni_<2;ni_++) \
        buf[kq_][ni_] = *(const short8*)(bp_ + ni_*4096 + kq_*32); }while(0)

    LOADH(bfb[0], 0);                      // prefetch drains with staging barrier anyway
    __syncthreads();                       // single barrier for the whole kernel

    int bb  = m0 >> 12;                    // batch (128 | 4096 so constant per block)
    int nl0 = m0 & 4095;
    int cn = lr, cr = lg*4;
    int swz = lr & 7;
    f32x4 acc[4][2];

#pragma unroll
    for (int h=0; h<8; h++){               // 8 half-tiles: nt = h>>1, hf = h&1
        int cur = h & 1;                   // compile-time under full unroll
        if (cur == 0){
#pragma unroll
            for (int mi=0;mi<4;mi++)
#pragma unroll
                for (int ni=0;ni<2;ni++) acc[mi][ni] = (f32x4){0.f,0.f,0.f,0.f};
        }
        if (h < 7) LOADH(bfb[cur^1], h+1); // issue next batch BEFORE compute
#pragma unroll
        for (int kq=0;kq<4;kq++){
            int ks = cur*4 + kq;
            short8 af[4];
#pragma unroll
            for (int mi=0;mi<4;mi++){
                int row = wr*64 + mi*16 + lr;
                int chp = (ks*4 + lg) ^ swz;
                af[mi] = *(const short8*)((const char*)As + row*512 + chp*16);
            }
#pragma unroll
            for (int mi=0;mi<4;mi++)
#pragma unroll
                for (int ni=0;ni<2;ni++)
                    acc[mi][ni] = __builtin_amdgcn_mfma_f32_16x16x32_bf16(af[mi], bfb[cur][kq][ni], acc[mi][ni], 0,0,0);
        }
        if (cur == 1){
            int nt = h >> 1;
            if (nt < 2){
                // kbuf: rows = tokens, cols = features
#pragma unroll
                for (int mi=0;mi<4;mi++)
#pragma unroll
                    for (int ni=0;ni<2;ni++)
#pragma unroll
                        for (int r=0;r<4;r++){
                            size_t gm = (size_t)m0 + wr*64 + mi*16 + cr + r;
                            int    gn = nt*128 + wc*32 + ni*16 + cn;
                            kb[gm*256 + gn] = f2bf(acc[mi][ni][r]);
                        }
            } else {
                // vT: [b][256 feat][4096 tok], ushort4 along token dim
#pragma unroll
                for (int mi=0;mi<4;mi++){
                    int nl = nl0 + wr*64 + mi*16 + cr;
#pragma unroll
                    for (int ni=0;ni<2;ni++){
                        int d = (nt-2)*128 + wc*32 + ni*16 + cn;
                        ushort4 o;
                        o.x = f2bf(acc[mi][ni][0]); o.y = f2bf(acc[mi][ni][1]);
                        o.z = f2bf(acc[mi][ni][2]); o.w = f2bf(acc[mi][ni][3]);
                        *(ushort4*)(vT + ((size_t)bb*256 + d)*4096 + nl) = o;
                    }
                }
            }
        }
    }
#undef LOADH
}

// ---------------- q = LN(slots) @ Wq^T -> bf16 [b][16][256] ----------------
__global__ __launch_bounds__(256) void k_q(const float* __restrict__ sn, const float* __restrict__ Wq,
                                           unsigned short* __restrict__ qbf){
    int b = blockIdx.x, c = threadIdx.x;
    const float4* wr = (const float4*)(Wq + (size_t)c*256);
    const float4* s4 = (const float4*)(sn + (size_t)b*Kk*Dd);
    float acc[15];
#pragma unroll
    for (int r=0;r<15;r++) acc[r] = 0.f;
    for (int e=0;e<64;e++){
        float4 wv = wr[e];
#pragma unroll
        for (int r=0;r<15;r++){
            float4 sv = s4[r*64+e];
            acc[r] += sv.x*wv.x + sv.y*wv.y + sv.z*wv.z + sv.w*wv.w;
        }
    }
#pragma unroll
    for (int r=0;r<15;r++) qbf[(size_t)b*4096 + r*256 + c] = f2bf(acc[r]);
    qbf[(size_t)b*4096 + 15*256 + c] = 0;
}

// ---------------- fused attention pass (MFMA) ----------------
// phase 2 restructured: each wave owns a distinct 64-wide d-range and loops all
// 4 n-windows -> no cross-wave accumulation, no LDS atomics, no updR buffer.
__global__ __launch_bounds__(256) void k_attn(const unsigned short* __restrict__ kbuf,
                                              const unsigned short* __restrict__ vT,
                                              const unsigned short* __restrict__ qbf,
                                              float* __restrict__ part, float* __restrict__ asum){
    __shared__ unsigned short qls[16*264];
    __shared__ unsigned short atn[4][16*72];
    __shared__ float asl[16];
    int tid = threadIdx.x;
    int w = tid >> 6, l = tid & 63;
    int b = blockIdx.y, n0 = blockIdx.x*256;
    if (tid < 16) asl[tid] = 0.f;
    {
        const short8* qg = (const short8*)(qbf + (size_t)b*4096);
        for (int i = tid; i < 512; i += 256){
            int row = i >> 5, cc = i & 31;
            *(short8*)&qls[row*264 + cc*8] = qg[i];
        }
    }
    __syncthreads();
    int lr = l & 15, lg = l >> 4;
    // phase 1: logits 16s x 64n per wave
    f32x4 acc[4];
#pragma unroll
    for (int t=0;t<4;t++) acc[t] = (f32x4){0.f,0.f,0.f,0.f};
    const unsigned short* kb = kbuf + ((size_t)(b*Nn) + n0 + w*64)*256;
#pragma unroll
    for (int ks=0; ks<8; ks++){
        short8 af = *(const short8*)&qls[lr*264 + ks*32 + lg*8];
#pragma unroll
        for (int t=0;t<4;t++){
            short8 bf = *(const short8*)(kb + ((size_t)(t*16+lr))*256 + ks*32 + lg*8);
            acc[t] = __builtin_amdgcn_mfma_f32_16x16x32_bf16(af, bf, acc[t], 0,0,0);
        }
    }
    // softmax over slots (per column n), write attn to LDS (bf16, A-layout ready)
    float asr[4] = {0.f,0.f,0.f,0.f};
#pragma unroll
    for (int t=0;t<4;t++){
        float v0=acc[t][0], v1=acc[t][1], v2=acc[t][2], v3=acc[t][3];
        if (lg==3) v3 = -1e30f;
        float m = fmaxf(fmaxf(v0,v1), fmaxf(v2,v3));
        m = fmaxf(m, __shfl_xor(m,16));
        m = fmaxf(m, __shfl_xor(m,32));
        float e0=__expf((v0-m)*0.0625f), e1=__expf((v1-m)*0.0625f),
              e2=__expf((v2-m)*0.0625f), e3=(lg==3)?0.f:__expf((v3-m)*0.0625f);
        float s = e0+e1+e2+e3;
        s += __shfl_xor(s,16); s += __shfl_xor(s,32);
        float inv = 1.f/s;
        e0*=inv; e1*=inv; e2*=inv; e3*=inv;
        unsigned short* a_ = &atn[w][0];
        int col = t*16 + lr;
        a_[(lg*4+0)*72+col] = f2bf(e0);
        a_[(lg*4+1)*72+col] = f2bf(e1);
        a_[(lg*4+2)*72+col] = f2bf(e2);
        a_[(lg*4+3)*72+col] = f2bf(e3);
        float p0=e0,p1=e1,p2=e2,p3=e3;
        for (int mk=1;mk<16;mk<<=1){
            p0+=__shfl_xor(p0,mk); p1+=__shfl_xor(p1,mk);
            p2+=__shfl_xor(p2,mk); p3+=__shfl_xor(p3,mk);
        }
        asr[0]+=p0; asr[1]+=p1; asr[2]+=p2; asr[3]+=p3;
    }
    if (lr == 0){
        atomicAdd(&asl[lg*4+0], asr[0]);
        atomicAdd(&asl[lg*4+1], asr[1]);
        atomicAdd(&asl[lg*4+2], asr[2]);
        atomicAdd(&asl[lg*4+3], asr[3]);
    }
    __syncthreads();   // atn[*] + asl complete
    // phase 2: wave w owns d-range [w*64, w*64+64); loops all 4 n-windows
    f32x4 ua[4];
#pragma unroll
    for (int dt=0;dt<4;dt++) ua[dt] = (f32x4){0.f,0.f,0.f,0.f};
    const unsigned short* vb = vT + (size_t)b*256*4096 + ((size_t)(w*64 + lr))*4096 + n0 + lg*8;
#pragma unroll
    for (int wn=0;wn<4;wn++)
#pragma unroll
        for (int kc=0;kc<2;kc++){
            short8 af = *(const short8*)&atn[wn][lr*72 + kc*32 + lg*8];
#pragma unroll
            for (int dt=0;dt<4;dt++){
                short8 bf = *(const short8*)(vb + (size_t)dt*16*4096 + wn*64 + kc*32);
                ua[dt] = __builtin_amdgcn_mfma_f32_16x16x32_bf16(af, bf, ua[dt], 0,0,0);
            }
        }
    float* pb = part + ((size_t)(b*16 + blockIdx.x))*4096;
#pragma unroll
    for (int dt=0;dt<4;dt++)
#pragma unroll
        for (int r=0;r<4;r++)
            pb[(lg*4+r)*256 + w*64 + dt*16 + lr] = ua[dt][r];
    if (tid < 15) atomicAdd(&asum[b*15+tid], asl[tid]);
}

__global__ __launch_bounds__(256) void k_upd_reduce(const float* __restrict__ part, float* __restrict__ upd){
    int i = blockIdx.x*256 + threadIdx.x;   // < 245760
    int b = i / 3840, rem = i - b*3840;
    const float* p = part + (size_t)b*16*4096 + rem;
    float s = 0.f;
#pragma unroll
    for (int j=0;j<16;j++) s += p[j*4096];
    upd[i] = s;
}

// ---------------- GRU gates ----------------
__global__ __launch_bounds__(256) void k_gates(const float* __restrict__ upd, const float* __restrict__ asum,
                                               const float* __restrict__ S,
                                               const float* __restrict__ wih, const float* __restrict__ whh,
                                               const float* __restrict__ bih, const float* __restrict__ bhh,
                                               float* __restrict__ gates){
    int b = blockIdx.y;
    int c = blockIdx.x*256 + threadIdx.x;
    bool isGI = (c < 768);
    const float* wrow = isGI ? (wih + (size_t)c*256) : (whh + (size_t)(c-768)*256);
    const float* src  = isGI ? (upd + (size_t)b*Kk*Dd) : (S + (size_t)b*Kk*Dd);
    float bias = isGI ? bih[c] : bhh[c-768];
    const float4* w4 = (const float4*)wrow;
    const float4* s4 = (const float4*)src;
    float acc[15];
#pragma unroll
    for (int r=0;r<15;r++) acc[r] = 0.f;
    for (int e=0;e<64;e++){
        float4 wv = w4[e];
#pragma unroll
        for (int r=0;r<15;r++){
            float4 sv = s4[r*64+e];
            acc[r] += sv.x*wv.x + sv.y*wv.y + sv.z*wv.z + sv.w*wv.w;
        }
    }
#pragma unroll
    for (int r=0;r<15;r++){
        float v = acc[r];
        if (isGI) v *= 1.f/(asum[b*Kk+r] + EPSN);
        gates[((size_t)(b*Kk+r))*1536 + c] = v + bias;
    }
}

__global__ __launch_bounds__(256) void k_gru(const float* __restrict__ gates, const float* __restrict__ S,
                                             float* __restrict__ G){
    int row = blockIdx.x, d = threadIdx.x;
    const float* gr = gates + (size_t)row*1536;
    float ir=gr[d], iz=gr[256+d], inn=gr[512+d];
    float hr=gr[768+d], hz=gr[1024+d], hn=gr[1280+d];
    float r = sigm_(ir+hr), z = sigm_(iz+hz);
    float n = tanh_(inn + r*hn);
    float h = S[(size_t)row*Dd + d];
    G[(size_t)row*Dd + d] = (1.f-z)*n + z*h;
}

__global__ __launch_bounds__(256) void k_mlp1(const float* __restrict__ sn, const float* __restrict__ w1,
                                              const float* __restrict__ b1, float* __restrict__ h1){
    int b = blockIdx.y;
    int c = blockIdx.x*256 + threadIdx.x;
    const float4* w4 = (const float4*)(w1 + (size_t)c*256);
    const float4* s4 = (const float4*)(sn + (size_t)b*Kk*Dd);
    float acc[15];
#pragma unroll
    for (int r=0;r<15;r++) acc[r] = 0.f;
    for (int e=0;e<64;e++){
        float4 wv = w4[e];
#pragma unroll
        for (int r=0;r<15;r++){
            float4 sv = s4[r*64+e];
            acc[r] += sv.x*wv.x + sv.y*wv.y + sv.z*wv.z + sv.w*wv.w;
        }
    }
    float bias = b1[c];
#pragma unroll
    for (int r=0;r<15;r++)
        h1[((size_t)(b*Kk+r))*Hh + c] = fmaxf(acc[r] + bias, 0.f);
}

__global__ __launch_bounds__(256) void k_mlp2(const float* __restrict__ G, const float* __restrict__ h1,
                                              const float* __restrict__ w2, const float* __restrict__ b2,
                                              float* __restrict__ S){
    int b = blockIdx.x, c = threadIdx.x;
    const float4* w4 = (const float4*)(w2 + (size_t)c*512);
    const float4* h4 = (const float4*)(h1 + (size_t)b*Kk*Hh);
    float acc[15];
#pragma unroll
    for (int r=0;r<15;r++) acc[r] = 0.f;
    for (int e=0;e<128;e++){
        float4 wv = w4[e];
#pragma unroll
        for (int r=0;r<15;r++){
            float4 hv = h4[r*128+e];
            acc[r] += hv.x*wv.x + hv.y*wv.y + hv.z*wv.z + hv.w*wv.w;
        }
    }
    float bias = b2[c];
#pragma unroll
    for (int r=0;r<15;r++){
        size_t i = ((size_t)(b*Kk+r))*Dd + c;
        S[i] = G[i] + acc[r] + bias;
    }
}

// ---------------- final attention output (MFMA logits + softmax) ----------------
__global__ __launch_bounds__(256) void k_attn_out(const unsigned short* __restrict__ kbuf,
                                                  const unsigned short* __restrict__ qbf,
                                                  float* __restrict__ out){
    __shared__ unsigned short qls[16*264];
    int tid = threadIdx.x;
    int w = tid >> 6, l = tid & 63;
    int b = blockIdx.y, n0 = blockIdx.x*256;
    {
        const short8* qg = (const short8*)(qbf + (size_t)b*4096);
        for (int i = tid; i < 512; i += 256){
            int row = i >> 5, cc = i & 31;
            *(short8*)&qls[row*264 + cc*8] = qg[i];
        }
    }
    __syncthreads();
    int lr = l & 15, lg = l >> 4;
    f32x4 acc[4];
#pragma unroll
    for (int t=0;t<4;t++) acc[t] = (f32x4){0.f,0.f,0.f,0.f};
    const unsigned short* kb = kbuf + ((size_t)(b*Nn) + n0 + w*64)*256;
#pragma unroll
    for (int ks=0; ks<8; ks++){
        short8 af = *(const short8*)&qls[lr*264 + ks*32 + lg*8];
#pragma unroll
        for (int t=0;t<4;t++){
            short8 bf = *(const short8*)(kb + ((size_t)(t*16+lr))*256 + ks*32 + lg*8);
            acc[t] = __builtin_amdgcn_mfma_f32_16x16x32_bf16(af, bf, acc[t], 0,0,0);
        }
    }
#pragma unroll
    for (int t=0;t<4;t++){
        float v0=acc[t][0], v1=acc[t][1], v2=acc[t][2], v3=acc[t][3];
        if (lg==3) v3 = -1e30f;
        float m = fmaxf(fmaxf(v0,v1), fmaxf(v2,v3));
        m = fmaxf(m, __shfl_xor(m,16));
        m = fmaxf(m, __shfl_xor(m,32));
        float e0=__expf((v0-m)*0.0625f), e1=__expf((v1-m)*0.0625f),
              e2=__expf((v2-m)*0.0625f), e3=(lg==3)?0.f:__expf((v3-m)*0.0625f);
        float s = e0+e1+e2+e3;
        s += __shfl_xor(s,16); s += __shfl_xor(s,32);
        float inv = 1.f/s;
        int n = n0 + w*64 + t*16 + lr;
        float ee0=e0*inv, ee1=e1*inv, ee2=e2*inv, ee3=e3*inv;
        out[((size_t)(b*15 + lg*4+0))*4096 + n] = ee0;
        out[((size_t)(b*15 + lg*4+1))*4096 + n] = ee1;
        out[((size_t)(b*15 + lg*4+2))*4096 + n] = ee2;
        if (lg != 3) out[((size_t)(b*15 + lg*4+3))*4096 + n] = ee3;
    }
}

__global__ __launch_bounds__(256) void k_copy(const float* __restrict__ src, float* __restrict__ dst){
    int i = blockIdx.x*256 + threadIdx.x;
    dst[i] = src[i];
}

extern "C" void kernel_launch(void* const* d_in, const int* in_sizes, int n_in,
                              void* d_out, int out_size, void* d_ws, size_t ws_size,
                              hipStream_t stream) {
    const float* inputs = (const float*)d_in[0];
    const float* noise  = (const float*)d_in[1];
    const float* mu     = (const float*)d_in[2];
    const float* lsig   = (const float*)d_in[3];
    const float* Wq     = (const float*)d_in[4];
    const float* Wk     = (const float*)d_in[5];
    const float* Wv     = (const float*)d_in[6];
    const float* wih    = (const float*)d_in[7];
    const float* whh    = (const float*)d_in[8];
    const float* bih    = (const float*)d_in[9];
    const float* bhh    = (const float*)d_in[10];
    const float* w1     = (const float*)d_in[11];
    const float* b1     = (const float*)d_in[12];
    const float* w2     = (const float*)d_in[13];
    const float* b2     = (const float*)d_in[14];
    const float* lin_w  = (const float*)d_in[15];
    const float* lin_b  = (const float*)d_in[16];
    const float* lsl_w  = (const float*)d_in[17];
    const float* lsl_b  = (const float*)d_in[18];
    const float* lml_w  = (const float*)d_in[19];
    const float* lml_b  = (const float*)d_in[20];

    char* ws = (char*)d_ws;
    unsigned short* xbf  = (unsigned short*)(ws + OFF_X);
    float*          PART = (float*)(ws + OFF_X);       // aliases xbf (dead after k_proj)
    unsigned short* kbuf = (unsigned short*)(ws + OFF_K);
    unsigned short* vT   = (unsigned short*)(ws + OFF_VT);
    unsigned short* wc   = (unsigned short*)(ws + OFF_WC);
    unsigned short* QBF  = (unsigned short*)(ws + OFF_QBF);
    float* S    = (float*)(ws + OFF_S);
    float* G    = (float*)(ws + OFF_G);
    float* SN   = (float*)(ws + OFF_SN);
    float* UPD  = (float*)(ws + OFF_UPD);
    float* ASUM = (float*)(ws + OFF_ASUM);
    float* GT   = (float*)(ws + OFF_GT);
    float* H1   = (float*)(ws + OFF_H1);
    float* out  = (float*)d_out;

    k_prep_wc<<<512, 256, 0, stream>>>(Wk, Wv, wc);
    k_slots_init<<<960, 256, 0, stream>>>(mu, lsig, noise, S);
    k_ln_in<<<BN/4, 256, 0, stream>>>(inputs, lin_w, lin_b, xbf);
    k_proj<<<BN/128, 512, 0, stream>>>(xbf, wc, kbuf, vT);

    for (int it = 0; it < 3; it++){
        k_ln_rows<<<240, 256, 0, stream>>>(S, lsl_w, lsl_b, SN);
        k_q<<<Bh, 256, 0, stream>>>(SN, Wq, QBF);
        hipMemsetAsync(ASUM, 0, 4096, stream);
        k_attn<<<dim3(16, Bh), 256, 0, stream>>>(kbuf, vT, QBF, PART, ASUM);
        k_upd_reduce<<<960, 256, 0, stream>>>(PART, UPD);
        k_gates<<<dim3(6, Bh), 256, 0, stream>>>(UPD, ASUM, S, wih, whh, bih, bhh, GT);
        k_gru<<<960, 256, 0, stream>>>(GT, S, G);
        k_ln_rows<<<240, 256, 0, stream>>>(G, lml_w, lml_b, SN);
        k_mlp1<<<dim3(2, Bh), 256, 0, stream>>>(SN, w1, b1, H1);
        k_mlp2<<<Bh, 256, 0, stream>>>(G, H1, w2, b2, S);
    }

    k_ln_rows<<<240, 256, 0, stream>>>(S, lsl_w, lsl_b, SN);
    k_q<<<Bh, 256, 0, stream>>>(SN, Wq, QBF);
    k_attn_out<<<dim3(16, Bh), 256, 0, stream>>>(kbuf, QBF, out + 245760);
    k_copy<<<960, 256, 0, stream>>>(S, out);
}